// Round 8
// baseline (118.265 us; speedup 1.0000x reference)
//
#include <hip/hip_runtime.h>

// FTDisentangledMHA: B=8, S=512, D=1024, H=16, Wd=64, MAX_REL=512 (span==S)
// scores(i,j) = scale*(q_i.k_j + q_i.pk[d] + k_j.pq[d]), d = i-j+511 (never clipped).
// q,pq pre-scaled by scale*log2e; softmax = exp2 with fixed max M=3.
// R8: attn_mega barriers 4->2 per jt: c2p strip kept WAVE-PRIVATE ([ip][84] region,
// unguarded store + intra-wave gather, no barrier); post-Pl barrier removed (Pl is
// per-wave; D2p/VT read-vs-next-write hazard is covered by the next arrival barrier).

typedef __bf16 bf16_t;
typedef __bf16 bf16x8 __attribute__((ext_vector_type(8)));
typedef __bf16 bf16x4 __attribute__((ext_vector_type(4)));
typedef float  f32x4  __attribute__((ext_vector_type(4)));

#define MFMA16(a, b, c) __builtin_amdgcn_mfma_f32_16x16x32_bf16((a), (b), (c), 0, 0, 0)
#define S2SCALE 0.10411754f   // (1/sqrt(192)) * log2(e)
#define MCONST  4.3280851f    // 3 * log2(e)

__device__ __forceinline__ void gload_lds16(const bf16_t* g, bf16_t* lds) {
  __builtin_amdgcn_global_load_lds(
      (const __attribute__((address_space(1))) void*)g,
      (__attribute__((address_space(3))) void*)lds, 16, 0, 0);
}

// chunk swizzle for row-major [rows][64] bf16 tiles staged as 16B chunks
__device__ __forceinline__ int kchunk(int row, int kg) {
  return row * 8 + (kg ^ (row & 7));
}

// ---------------------------------------------------------------- fp32 -> bf16 (all 5 arrays)
__global__ __launch_bounds__(256) void cvt_all(
    const float* __restrict__ x, const float* __restrict__ rel,
    const float* __restrict__ wq, const float* __restrict__ wk, const float* __restrict__ wv,
    bf16_t* __restrict__ out) {
  const size_t i = ((size_t)blockIdx.x * 256 + threadIdx.x) * 4;
  const float* src; size_t off;
  if (i < 4194304) { src = x; off = i; }
  else {
    size_t j = i - 4194304; int sel = (int)(j >> 20); off = j & 1048575;
    src = sel == 0 ? wq : sel == 1 ? wk : sel == 2 ? wv : rel;
  }
  float4 v = *reinterpret_cast<const float4*>(src + off);
  bf16x4 o;
  o[0] = (bf16_t)v.x; o[1] = (bf16_t)v.y; o[2] = (bf16_t)v.z; o[3] = (bf16_t)v.w;
  *reinterpret_cast<bf16x4*>(out + i) = o;
}

// ------------------------------------------------- 256^2-tile 8-phase projection GEMM (R6)
__device__ __forceinline__ void stage_tile(const bf16_t* base, int T, bf16_t* lds, int tid) {
#pragma unroll
  for (int i = 0; i < 2; ++i) {
    const int c = tid + i * 512;
    const int row = c >> 2, kg = (c & 3) ^ (row & 3);
    gload_lds16(base + (size_t)row * 1024 + T * 32 + kg * 8, lds + c * 8);
  }
}

#define VMW2 asm volatile("s_waitcnt vmcnt(2)" ::: "memory")
#define VMW0 asm volatile("s_waitcnt vmcnt(0)" ::: "memory")
#define NOPS ((void)0)

#define PH_BODY(AB, BB, FH, READB, STAGE_STMT, WAIT_STMT)                               \
  {                                                                                     \
    if (READB) {                                                                        \
      _Pragma("unroll") for (int n_ = 0; n_ < 4; ++n_)                                  \
        bfr[n_] = *reinterpret_cast<const bf16x8*>(                                     \
            (BB) + (((wn * 64 + n_ * 16 + li) * 4 + (gr ^ (li & 3))) * 8));             \
    }                                                                                   \
    bf16x8 af_[4];                                                                      \
    _Pragma("unroll") for (int a_ = 0; a_ < 4; ++a_)                                    \
      af_[a_] = *reinterpret_cast<const bf16x8*>(                                       \
          (AB) + (((wm * 128 + ((FH) * 4 + a_) * 16 + li) * 4 + (gr ^ (li & 3))) * 8)); \
    STAGE_STMT;                                                                         \
    __builtin_amdgcn_s_barrier();                                                       \
    asm volatile("s_waitcnt lgkmcnt(0)" ::: "memory");                                  \
    __builtin_amdgcn_sched_barrier(0);                                                  \
    __builtin_amdgcn_s_setprio(1);                                                      \
    _Pragma("unroll") for (int a_ = 0; a_ < 4; ++a_)                                    \
      _Pragma("unroll") for (int n_ = 0; n_ < 4; ++n_)                                  \
        acc[(FH) * 4 + a_][n_] = MFMA16(af_[a_], bfr[n_], acc[(FH) * 4 + a_][n_]);      \
    __builtin_amdgcn_s_setprio(0);                                                      \
    WAIT_STMT;                                                                          \
    __builtin_amdgcn_s_barrier();                                                       \
    __builtin_amdgcn_sched_barrier(0);                                                  \
  }

__global__ __launch_bounds__(512, 2) void gemm_qkv(
    const bf16_t* __restrict__ xb, const bf16_t* __restrict__ reb,
    const bf16_t* __restrict__ wqb, const bf16_t* __restrict__ wkb, const bf16_t* __restrict__ wvb,
    const float* __restrict__ bq, const float* __restrict__ bk, const float* __restrict__ bv,
    bf16_t* __restrict__ qo, bf16_t* __restrict__ ko, bf16_t* __restrict__ vo,
    bf16_t* __restrict__ pko, bf16_t* __restrict__ pqo) {
  __shared__ bf16_t Abuf[2][8192];
  __shared__ bf16_t Bbuf[2][8192];

  const int bid0 = blockIdx.x;
  const int bid = (bid0 & 7) * 28 + (bid0 >> 3);  // 224 = 8*28, bijective XCD chunks
  const int tid = threadIdx.x;
  const int wave = tid >> 6;
  const int wm = wave >> 2, wn = wave & 3;
  const int l = tid & 63, li = l & 15, gr = l >> 4;

  const bf16_t* Abase; const bf16_t* Bbase; const float* bias; float sc;
  bf16_t* Cout; int row0, col0;
  if (bid < 192) {  // main: x (4096) x [Wq|Wk|Wv] (3072)
    const int bx = bid / 12, by = bid % 12;
    Abase = xb + (size_t)bx * 262144; row0 = bx * 256;
    const int wsel = by >> 2;
    Bbase = (wsel == 0 ? wqb : wsel == 1 ? wkb : wvb) + (size_t)(by & 3) * 262144;
    bias = wsel == 0 ? bq : wsel == 1 ? bk : bv;
    sc = wsel == 0 ? S2SCALE : 1.f;
    Cout = wsel == 0 ? qo : wsel == 1 ? ko : vo;
    col0 = (by & 3) * 256;
  } else {  // pos: re (1024) x [Wk|Wq] (2048)
    const int p = bid - 192;
    const int bx = p >> 3, by = p & 7;
    Abase = reb + (size_t)bx * 262144; row0 = bx * 256;
    const int wsel = by >> 2;
    Bbase = (wsel == 0 ? wkb : wqb) + (size_t)(by & 3) * 262144;
    bias = wsel == 0 ? bk : bq;
    sc = wsel == 0 ? 1.f : S2SCALE;
    Cout = wsel == 0 ? pko : pqo;
    col0 = (by & 3) * 256;
  }

  f32x4 acc[8][4] = {};
  bf16x8 bfr[4];

  stage_tile(Abase, 0, Abuf[0], tid);
  stage_tile(Bbase, 0, Bbuf[0], tid);
  stage_tile(Bbase, 1, Bbuf[1], tid);
  VMW2;
  __builtin_amdgcn_s_barrier();
  __builtin_amdgcn_sched_barrier(0);

  for (int t = 0; t < 15; ++t) {
    const int T0 = 2 * t;
    PH_BODY(Abuf[0], Bbuf[0], 0, true,  stage_tile(Abase, T0 + 1, Abuf[1], tid), NOPS);
    PH_BODY(Abuf[0], Bbuf[0], 1, false, stage_tile(Bbase, T0 + 2, Bbuf[0], tid), VMW2);
    PH_BODY(Abuf[1], Bbuf[1], 0, true,  stage_tile(Abase, T0 + 2, Abuf[0], tid), NOPS);
    PH_BODY(Abuf[1], Bbuf[1], 1, false, stage_tile(Bbase, T0 + 3, Bbuf[1], tid), VMW2);
  }
  PH_BODY(Abuf[0], Bbuf[0], 0, true,  stage_tile(Abase, 31, Abuf[1], tid), NOPS);
  PH_BODY(Abuf[0], Bbuf[0], 1, false, NOPS, VMW0);
  PH_BODY(Abuf[1], Bbuf[1], 0, true,  NOPS, NOPS);
  PH_BODY(Abuf[1], Bbuf[1], 1, false, NOPS, NOPS);

#pragma unroll
  for (int a = 0; a < 8; ++a)
#pragma unroll
    for (int n = 0; n < 4; ++n) {
      const int col = col0 + wn * 64 + n * 16 + li;
      const float bv_ = bias[col];
#pragma unroll
      for (int r = 0; r < 4; ++r) {
        const int row = row0 + wm * 128 + a * 16 + gr * 4 + r;
        Cout[(size_t)row * 1024 + col] = (bf16_t)((acc[a][n][r] + bv_) * sc);
      }
    }
}

// ---------------------------------------------------------------- fused attention + bias
// 512 blocks = (bh, qt-pair); 8 waves: qh = wave>>2 selects qt = 2*qp+qh, wv = wave&3
// owns 16 q-rows. pk/pq staged once per block as ring-of-4 64-row segments.
__global__ __launch_bounds__(512) void attn_mega(
    const bf16_t* __restrict__ qb, const bf16_t* __restrict__ kb,
    const bf16_t* __restrict__ vb, const bf16_t* __restrict__ pkb,
    const bf16_t* __restrict__ pqb, float* __restrict__ out) {
  const int bid0 = blockIdx.x;
  const int bid = (bid0 & 7) * 64 + (bid0 >> 3);  // 512 = 8*64, XCD chunks
  const int qp = bid & 3;
  const int bh = bid >> 2;
  const int h = bh & 15, b = bh >> 4;
  const int i0base = qp * 128;
  const int tid = threadIdx.x;
  const int w = tid >> 6, l = tid & 63;
  const int qh = w >> 2, wv = w & 3;
  const int li = l & 15, gr = l >> 4;
  const int i0 = i0base + qh * 64;

  __shared__ bf16_t Ks[2][4096];      // K tile dbuf, kchunk layout
  __shared__ bf16_t PKs[4][4096];     // pk ring: local seg s -> slot s&3
  __shared__ bf16_t PQs[4][4096];
  __shared__ bf16_t VT[4096];         // transposed V, chunk-swizzled
  __shared__ bf16_t Pl[8][1024];      // per-wave P A-frags
  __shared__ bf16_t Dcp[8][16 * 84];  // c2p per-WAVE private strip [ip][ci], pad 84
  __shared__ bf16_t D2p[2][64][72];   // p2c as [jj][ii] per qh (cross-wave)

  // stage one 64x64 tile (512 threads, 1 chunk each) into kchunk layout
#define STG(gsrc, lds) { int s_ = tid ^ ((tid >> 3) & 7);                              \
    gload_lds16((gsrc) + (size_t)(s_ >> 3) * 1024 + (s_ & 7) * 8, (lds) + tid * 8); }

  // Q fragments (direct global; q pre-scaled by S2SCALE)
  const bf16_t* qptr = qb + (size_t)(b * 512 + i0 + wv * 16 + li) * 1024 + h * 64 + gr * 8;
  const bf16x8 aq0 = *reinterpret_cast<const bf16x8*>(qptr);
  const bf16x8 aq1 = *reinterpret_cast<const bf16x8*>(qptr + 32);

  const bf16_t* kbase = kb + (size_t)(b * 512) * 1024 + h * 64;
  const bf16_t* vbase = vb + (size_t)(b * 512) * 1024 + h * 64;
  const bf16_t* pkw = pkb + (size_t)i0base * 1024 + h * 64;  // local row g: abs d = i0base+g
  const bf16_t* pqw = pqb + (size_t)i0base * 1024 + h * 64;

  f32x4 acc[4] = {};
  float lsum[4] = {0.f, 0.f, 0.f, 0.f};
  bf16x8 vreg[2];

  // prologue: K(0), pk/pq segs 7..9, V(0)
  STG(kbase, Ks[0]);
#pragma unroll
  for (int s = 7; s <= 9; ++s) {
    STG(pkw + (size_t)s * 65536, PKs[s & 3]);
    STG(pqw + (size_t)s * 65536, PQs[s & 3]);
  }
  vreg[0] = *reinterpret_cast<const bf16x8*>(vbase + (size_t)(tid >> 3) * 1024 + (tid & 7) * 8);

#pragma unroll
  for (int jt = 0; jt < 8; ++jt) {
    const int cur = jt & 1;
    const int sb = qh + 7 - jt;  // local seg index of this wave's window base

    // arrival barrier: prefetched data landed; prev jt's D2p/VT reads + PV done
    asm volatile("s_waitcnt vmcnt(0)" ::: "memory");
    __builtin_amdgcn_s_barrier();
    __builtin_amdgcn_sched_barrier(0);

    // prefetch jt+1 (in flight across the mid barrier)
    if (jt < 7) {
      STG(kbase + (size_t)(jt + 1) * 65536, Ks[cur ^ 1]);
      const int sg = 6 - jt;
      STG(pkw + (size_t)sg * 65536, PKs[sg & 3]);
      STG(pqw + (size_t)sg * 65536, PQs[sg & 3]);
      vreg[cur ^ 1] = *reinterpret_cast<const bf16x8*>(
          vbase + (size_t)((jt + 1) * 64 + (tid >> 3)) * 1024 + (tid & 7) * 8);
    }

    // VT build from V regs
    {
      const int j = tid >> 3, w0 = (tid & 7) * 8;
      bf16x8 vv = vreg[cur];
#pragma unroll
      for (int e = 0; e < 8; ++e) {
        int ch = (j >> 3) * 64 + w0 + e;
        ch ^= ((ch >> 3) & 7);
        VT[ch * 8 + (j & 7)] = vv[e];
      }
    }

    __builtin_amdgcn_s_setprio(1);
    // QK^T
    f32x4 sfr[4];
#pragma unroll
    for (int n = 0; n < 4; ++n) {
      const int j_ = n * 16 + li;
      bf16x8 b0 = *reinterpret_cast<const bf16x8*>(Ks[cur] + kchunk(j_, gr) * 8);
      bf16x8 b1 = *reinterpret_cast<const bf16x8*>(Ks[cur] + kchunk(j_, 4 + gr) * 8);
      f32x4 t = {};
      t = MFMA16(aq0, b0, t);
      t = MFMA16(aq1, b1, t);
      sfr[n] = t;
    }

    // c2p strip (WAVE-PRIVATE): Dcp[w][ip][ci], ci = ip + 63 - jj; unguarded stores
#pragma unroll
    for (int cg = 0; cg < 5; ++cg) {
      const int b16 = wv + cg;
      const int slot = (sb + (b16 >> 2)) & 3;
      const int r64 = (b16 & 3) * 16 + li;
      bf16x8 p0 = *reinterpret_cast<const bf16x8*>(PKs[slot] + kchunk(r64, gr) * 8);
      bf16x8 p1 = *reinterpret_cast<const bf16x8*>(PKs[slot] + kchunk(r64, 4 + gr) * 8);
      f32x4 d = {};
      d = MFMA16(aq0, p0, d);
      d = MFMA16(aq1, p1, d);
#pragma unroll
      for (int r = 0; r < 4; ++r)
        Dcp[w][(gr * 4 + r) * 84 + cg * 16 + li] = (bf16_t)d[r];
    }

    // p2c strip: wave covers jj in [wv*16,+16), stored D2p[jj][ii] (cross-wave)
    const bf16x8 ak0 = *reinterpret_cast<const bf16x8*>(Ks[cur] + kchunk(wv * 16 + li, gr) * 8);
    const bf16x8 ak1 = *reinterpret_cast<const bf16x8*>(Ks[cur] + kchunk(wv * 16 + li, 4 + gr) * 8);
#pragma unroll
    for (int cg = 0; cg < 5; ++cg) {
      const int b16 = 3 - wv + cg;
      const int slot = (sb + (b16 >> 2)) & 3;
      const int r64 = (b16 & 3) * 16 + li;
      bf16x8 p0 = *reinterpret_cast<const bf16x8*>(PQs[slot] + kchunk(r64, gr) * 8);
      bf16x8 p1 = *reinterpret_cast<const bf16x8*>(PQs[slot] + kchunk(r64, 4 + gr) * 8);
      f32x4 d = {};
      d = MFMA16(ak0, p0, d);
      d = MFMA16(ak1, p1, d);
#pragma unroll
      for (int r = 0; r < 4; ++r) {
        const int jp = gr * 4 + r;               // jj within strip
        const int iis = cg * 16 + li + jp - 15;  // ii = col + jj' - 15
        if ((unsigned)iis < 64u) D2p[qh][wv * 16 + jp][iis] = (bf16_t)d[r];
      }
    }
    __builtin_amdgcn_s_setprio(0);

    // mid barrier: VT + D2p cross-wave visible (Dcp/Pl need no barrier: per-wave)
    asm volatile("s_waitcnt lgkmcnt(0)" ::: "memory");
    __builtin_amdgcn_s_barrier();
    __builtin_amdgcn_sched_barrier(0);

    // gather biases + softmax + Pl (all remaining LDS deps are wave-private or synced)
#pragma unroll
    for (int n = 0; n < 4; ++n) {
      const bf16x4 pvv = *reinterpret_cast<const bf16x4*>(&D2p[qh][n * 16 + li][wv * 16 + gr * 4]);
#pragma unroll
      for (int r = 0; r < 4; ++r) {
        const int ip = gr * 4 + r;
        const float c2 = (float)Dcp[w][ip * 84 + ip + 63 - n * 16 - li];
        const float s = sfr[n][r] + c2 + (float)pvv[r] - MCONST;
        const float pe = __builtin_amdgcn_exp2f(s);
        lsum[r] += pe;
        int ch = (n * 2 + (li >> 3)) * 16 + gr * 4 + r;
        ch ^= ((ch >> 3) & 7);
        Pl[w][ch * 8 + (li & 7)] = (bf16_t)pe;
      }
    }

    // Pl is per-wave: only drain LDS, no barrier before PV
    asm volatile("s_waitcnt lgkmcnt(0)" ::: "memory");
    __builtin_amdgcn_sched_barrier(0);

    // PV
    __builtin_amdgcn_s_setprio(1);
#pragma unroll
    for (int ks = 0; ks < 2; ++ks) {
      int chA = (ks * 4 + gr) * 16 + li;
      chA ^= ((chA >> 3) & 7);
      bf16x8 ap = *reinterpret_cast<const bf16x8*>(Pl[w] + chA * 8);
#pragma unroll
      for (int n2 = 0; n2 < 4; ++n2) {
        int chB = (ks * 4 + gr) * 64 + n2 * 16 + li;
        chB ^= ((chB >> 3) & 7);
        bf16x8 bvf = *reinterpret_cast<const bf16x8*>(VT + chB * 8);
        acc[n2] = MFMA16(ap, bvf, acc[n2]);
      }
    }
    __builtin_amdgcn_s_setprio(0);
  }
#undef STG

  // reduce lsum across the 16 li lanes, normalize, store
#pragma unroll
  for (int mm = 1; mm < 16; mm <<= 1)
#pragma unroll
    for (int r = 0; r < 4; ++r)
      lsum[r] += __shfl_xor(lsum[r], mm, 64);
  float invl[4];
#pragma unroll
  for (int r = 0; r < 4; ++r) invl[r] = 1.0f / lsum[r];

#pragma unroll
  for (int n2 = 0; n2 < 4; ++n2)
#pragma unroll
    for (int r = 0; r < 4; ++r) {
      const int i = i0 + wv * 16 + gr * 4 + r;
      const int wcol = n2 * 16 + li;
      out[(size_t)(b * 512 + i) * 1024 + h * 64 + wcol] = acc[n2][r] * invl[r];
    }
}

// ---------------------------------------------------------------- launch
extern "C" void kernel_launch(void* const* d_in, const int* in_sizes, int n_in,
                              void* d_out, int out_size, void* d_ws, size_t ws_size,
                              hipStream_t stream) {
  (void)in_sizes; (void)n_in; (void)out_size; (void)ws_size;
  const float* x   = (const float*)d_in[0];
  const float* rel = (const float*)d_in[1];
  const float* Wq  = (const float*)d_in[2];
  const float* bq  = (const float*)d_in[3];
  const float* Wk  = (const float*)d_in[4];
  const float* bk  = (const float*)d_in[5];
  const float* Wv  = (const float*)d_in[6];
  const float* bv  = (const float*)d_in[7];
  float* out = (float*)d_out;

  bf16_t* ws  = (bf16_t*)d_ws;
  bf16_t* xb  = ws;                 // 4 M elems
  bf16_t* wqb = xb + 4194304;       // 1 M each
  bf16_t* wkb = wqb + 1048576;
  bf16_t* wvb = wkb + 1048576;
  bf16_t* reb = wvb + 1048576;
  bf16_t* qbuf = reb + 1048576;     // 4 M each
  bf16_t* kbuf = qbuf + 4194304;
  bf16_t* vbuf = kbuf + 4194304;
  bf16_t* pkb = vbuf + 4194304;     // 1 M each
  bf16_t* pqb = pkb + 1048576;      // total ws ~44 MB

  cvt_all<<<8192, 256, 0, stream>>>(x, rel, Wq, Wk, Wv, ws);
  gemm_qkv<<<224, 512, 0, stream>>>(xb, reb, wqb, wkb, wvb,
                                    bq, bk, bv, qbuf, kbuf, vbuf, pkb, pqb);
  attn_mega<<<512, 512, 0, stream>>>(qbuf, kbuf, vbuf, pkb, pqb, out);
}

// Round 9
// 108.650 us; speedup vs baseline: 1.0885x; 1.0885x over previous
//
#include <hip/hip_runtime.h>

// FTDisentangledMHA: B=8, S=512, D=1024, H=16, Wd=64, MAX_REL=512 (span==S)
// scores(i,j) = scale*(q_i.k_j + q_i.pk[d] + k_j.pq[d]), d = i-j+511 (never clipped).
// q,pq pre-scaled by scale*log2e; softmax = exp2 with fixed max M=3.
// R9: LDS-instr diet in attn_mega: c2p strip stored TRANSPOSED ([u][ip], b64x5 instead
// of 20 scalar stores); p2c strip padded [64][100] (+16 shift) -> unguarded stores,
// b64 gather kept; cvt_all vectorized to 16B stores.

typedef __bf16 bf16_t;
typedef __bf16 bf16x8 __attribute__((ext_vector_type(8)));
typedef __bf16 bf16x4 __attribute__((ext_vector_type(4)));
typedef float  f32x4  __attribute__((ext_vector_type(4)));

#define MFMA16(a, b, c) __builtin_amdgcn_mfma_f32_16x16x32_bf16((a), (b), (c), 0, 0, 0)
#define S2SCALE 0.10411754f   // (1/sqrt(192)) * log2(e)
#define MCONST  4.3280851f    // 3 * log2(e)

__device__ __forceinline__ void gload_lds16(const bf16_t* g, bf16_t* lds) {
  __builtin_amdgcn_global_load_lds(
      (const __attribute__((address_space(1))) void*)g,
      (__attribute__((address_space(3))) void*)lds, 16, 0, 0);
}

// chunk swizzle for row-major [rows][64] bf16 tiles staged as 16B chunks
__device__ __forceinline__ int kchunk(int row, int kg) {
  return row * 8 + (kg ^ (row & 7));
}

// ---------------------------------------------------------------- fp32 -> bf16 (all 5 arrays)
__global__ __launch_bounds__(256) void cvt_all(
    const float* __restrict__ x, const float* __restrict__ rel,
    const float* __restrict__ wq, const float* __restrict__ wk, const float* __restrict__ wv,
    bf16_t* __restrict__ out) {
  const size_t i = ((size_t)blockIdx.x * 256 + threadIdx.x) * 8;
  const float* src; size_t off;
  if (i < 4194304) { src = x; off = i; }
  else {
    size_t j = i - 4194304; int sel = (int)(j >> 20); off = j & 1048575;
    src = sel == 0 ? wq : sel == 1 ? wk : sel == 2 ? wv : rel;
  }
  float4 v0 = *reinterpret_cast<const float4*>(src + off);
  float4 v1 = *reinterpret_cast<const float4*>(src + off + 4);
  bf16x8 o;
  o[0] = (bf16_t)v0.x; o[1] = (bf16_t)v0.y; o[2] = (bf16_t)v0.z; o[3] = (bf16_t)v0.w;
  o[4] = (bf16_t)v1.x; o[5] = (bf16_t)v1.y; o[6] = (bf16_t)v1.z; o[7] = (bf16_t)v1.w;
  *reinterpret_cast<bf16x8*>(out + i) = o;
}

// ------------------------------------------------- 256^2-tile 8-phase projection GEMM (R6)
__device__ __forceinline__ void stage_tile(const bf16_t* base, int T, bf16_t* lds, int tid) {
#pragma unroll
  for (int i = 0; i < 2; ++i) {
    const int c = tid + i * 512;
    const int row = c >> 2, kg = (c & 3) ^ (row & 3);
    gload_lds16(base + (size_t)row * 1024 + T * 32 + kg * 8, lds + c * 8);
  }
}

#define VMW2 asm volatile("s_waitcnt vmcnt(2)" ::: "memory")
#define VMW0 asm volatile("s_waitcnt vmcnt(0)" ::: "memory")
#define NOPS ((void)0)

#define PH_BODY(AB, BB, FH, READB, STAGE_STMT, WAIT_STMT)                               \
  {                                                                                     \
    if (READB) {                                                                        \
      _Pragma("unroll") for (int n_ = 0; n_ < 4; ++n_)                                  \
        bfr[n_] = *reinterpret_cast<const bf16x8*>(                                     \
            (BB) + (((wn * 64 + n_ * 16 + li) * 4 + (gr ^ (li & 3))) * 8));             \
    }                                                                                   \
    bf16x8 af_[4];                                                                      \
    _Pragma("unroll") for (int a_ = 0; a_ < 4; ++a_)                                    \
      af_[a_] = *reinterpret_cast<const bf16x8*>(                                       \
          (AB) + (((wm * 128 + ((FH) * 4 + a_) * 16 + li) * 4 + (gr ^ (li & 3))) * 8)); \
    STAGE_STMT;                                                                         \
    __builtin_amdgcn_s_barrier();                                                       \
    asm volatile("s_waitcnt lgkmcnt(0)" ::: "memory");                                  \
    __builtin_amdgcn_sched_barrier(0);                                                  \
    __builtin_amdgcn_s_setprio(1);                                                      \
    _Pragma("unroll") for (int a_ = 0; a_ < 4; ++a_)                                    \
      _Pragma("unroll") for (int n_ = 0; n_ < 4; ++n_)                                  \
        acc[(FH) * 4 + a_][n_] = MFMA16(af_[a_], bfr[n_], acc[(FH) * 4 + a_][n_]);      \
    __builtin_amdgcn_s_setprio(0);                                                      \
    WAIT_STMT;                                                                          \
    __builtin_amdgcn_s_barrier();                                                       \
    __builtin_amdgcn_sched_barrier(0);                                                  \
  }

__global__ __launch_bounds__(512, 2) void gemm_qkv(
    const bf16_t* __restrict__ xb, const bf16_t* __restrict__ reb,
    const bf16_t* __restrict__ wqb, const bf16_t* __restrict__ wkb, const bf16_t* __restrict__ wvb,
    const float* __restrict__ bq, const float* __restrict__ bk, const float* __restrict__ bv,
    bf16_t* __restrict__ qo, bf16_t* __restrict__ ko, bf16_t* __restrict__ vo,
    bf16_t* __restrict__ pko, bf16_t* __restrict__ pqo) {
  __shared__ bf16_t Abuf[2][8192];
  __shared__ bf16_t Bbuf[2][8192];

  const int bid0 = blockIdx.x;
  const int bid = (bid0 & 7) * 28 + (bid0 >> 3);  // 224 = 8*28, bijective XCD chunks
  const int tid = threadIdx.x;
  const int wave = tid >> 6;
  const int wm = wave >> 2, wn = wave & 3;
  const int l = tid & 63, li = l & 15, gr = l >> 4;

  const bf16_t* Abase; const bf16_t* Bbase; const float* bias; float sc;
  bf16_t* Cout; int row0, col0;
  if (bid < 192) {  // main: x (4096) x [Wq|Wk|Wv] (3072)
    const int bx = bid / 12, by = bid % 12;
    Abase = xb + (size_t)bx * 262144; row0 = bx * 256;
    const int wsel = by >> 2;
    Bbase = (wsel == 0 ? wqb : wsel == 1 ? wkb : wvb) + (size_t)(by & 3) * 262144;
    bias = wsel == 0 ? bq : wsel == 1 ? bk : bv;
    sc = wsel == 0 ? S2SCALE : 1.f;
    Cout = wsel == 0 ? qo : wsel == 1 ? ko : vo;
    col0 = (by & 3) * 256;
  } else {  // pos: re (1024) x [Wk|Wq] (2048)
    const int p = bid - 192;
    const int bx = p >> 3, by = p & 7;
    Abase = reb + (size_t)bx * 262144; row0 = bx * 256;
    const int wsel = by >> 2;
    Bbase = (wsel == 0 ? wkb : wqb) + (size_t)(by & 3) * 262144;
    bias = wsel == 0 ? bk : bq;
    sc = wsel == 0 ? 1.f : S2SCALE;
    Cout = wsel == 0 ? pko : pqo;
    col0 = (by & 3) * 256;
  }

  f32x4 acc[8][4] = {};
  bf16x8 bfr[4];

  stage_tile(Abase, 0, Abuf[0], tid);
  stage_tile(Bbase, 0, Bbuf[0], tid);
  stage_tile(Bbase, 1, Bbuf[1], tid);
  VMW2;
  __builtin_amdgcn_s_barrier();
  __builtin_amdgcn_sched_barrier(0);

  for (int t = 0; t < 15; ++t) {
    const int T0 = 2 * t;
    PH_BODY(Abuf[0], Bbuf[0], 0, true,  stage_tile(Abase, T0 + 1, Abuf[1], tid), NOPS);
    PH_BODY(Abuf[0], Bbuf[0], 1, false, stage_tile(Bbase, T0 + 2, Bbuf[0], tid), VMW2);
    PH_BODY(Abuf[1], Bbuf[1], 0, true,  stage_tile(Abase, T0 + 2, Abuf[0], tid), NOPS);
    PH_BODY(Abuf[1], Bbuf[1], 1, false, stage_tile(Bbase, T0 + 3, Bbuf[1], tid), VMW2);
  }
  PH_BODY(Abuf[0], Bbuf[0], 0, true,  stage_tile(Abase, 31, Abuf[1], tid), NOPS);
  PH_BODY(Abuf[0], Bbuf[0], 1, false, NOPS, VMW0);
  PH_BODY(Abuf[1], Bbuf[1], 0, true,  NOPS, NOPS);
  PH_BODY(Abuf[1], Bbuf[1], 1, false, NOPS, NOPS);

#pragma unroll
  for (int a = 0; a < 8; ++a)
#pragma unroll
    for (int n = 0; n < 4; ++n) {
      const int col = col0 + wn * 64 + n * 16 + li;
      const float bv_ = bias[col];
#pragma unroll
      for (int r = 0; r < 4; ++r) {
        const int row = row0 + wm * 128 + a * 16 + gr * 4 + r;
        Cout[(size_t)row * 1024 + col] = (bf16_t)((acc[a][n][r] + bv_) * sc);
      }
    }
}

// ---------------------------------------------------------------- fused attention + bias
// 512 blocks = (bh, qt-pair); 8 waves: qh = wave>>2 selects qt = 2*qp+qh, wv = wave&3
// owns 16 q-rows. pk/pq staged once per block as ring-of-4 64-row segments.
__global__ __launch_bounds__(512) void attn_mega(
    const bf16_t* __restrict__ qb, const bf16_t* __restrict__ kb,
    const bf16_t* __restrict__ vb, const bf16_t* __restrict__ pkb,
    const bf16_t* __restrict__ pqb, float* __restrict__ out) {
  const int bid0 = blockIdx.x;
  const int bid = (bid0 & 7) * 64 + (bid0 >> 3);  // 512 = 8*64, XCD chunks
  const int qp = bid & 3;
  const int bh = bid >> 2;
  const int h = bh & 15, b = bh >> 4;
  const int i0base = qp * 128;
  const int tid = threadIdx.x;
  const int w = tid >> 6, l = tid & 63;
  const int qh = w >> 2, wv = w & 3;
  const int li = l & 15, gr = l >> 4;
  const int i0 = i0base + qh * 64;

  __shared__ bf16_t Ks[2][4096];      // K tile dbuf, kchunk layout
  __shared__ bf16_t PKs[4][4096];     // pk ring: local seg s -> slot s&3
  __shared__ bf16_t PQs[4][4096];
  __shared__ bf16_t VT[4096];         // transposed V, chunk-swizzled
  __shared__ bf16_t Pl[8][1024];      // per-wave P A-frags
  __shared__ bf16_t DcpT[8][80][20];  // c2p per-WAVE, TRANSPOSED [u][ip] (b64 stores)
  __shared__ bf16_t D2p[2][64][100];  // p2c [jj][ii+16] per qh, padded (unguarded)

  // stage one 64x64 tile (512 threads, 1 chunk each) into kchunk layout
#define STG(gsrc, lds) { int s_ = tid ^ ((tid >> 3) & 7);                              \
    gload_lds16((gsrc) + (size_t)(s_ >> 3) * 1024 + (s_ & 7) * 8, (lds) + tid * 8); }

  // Q fragments (direct global; q pre-scaled by S2SCALE)
  const bf16_t* qptr = qb + (size_t)(b * 512 + i0 + wv * 16 + li) * 1024 + h * 64 + gr * 8;
  const bf16x8 aq0 = *reinterpret_cast<const bf16x8*>(qptr);
  const bf16x8 aq1 = *reinterpret_cast<const bf16x8*>(qptr + 32);

  const bf16_t* kbase = kb + (size_t)(b * 512) * 1024 + h * 64;
  const bf16_t* vbase = vb + (size_t)(b * 512) * 1024 + h * 64;
  const bf16_t* pkw = pkb + (size_t)i0base * 1024 + h * 64;  // local row g: abs d = i0base+g
  const bf16_t* pqw = pqb + (size_t)i0base * 1024 + h * 64;

  f32x4 acc[4] = {};
  float lsum[4] = {0.f, 0.f, 0.f, 0.f};
  bf16x8 vreg[2];

  // prologue: K(0), pk/pq segs 7..9, V(0)
  STG(kbase, Ks[0]);
#pragma unroll
  for (int s = 7; s <= 9; ++s) {
    STG(pkw + (size_t)s * 65536, PKs[s & 3]);
    STG(pqw + (size_t)s * 65536, PQs[s & 3]);
  }
  vreg[0] = *reinterpret_cast<const bf16x8*>(vbase + (size_t)(tid >> 3) * 1024 + (tid & 7) * 8);

#pragma unroll
  for (int jt = 0; jt < 8; ++jt) {
    const int cur = jt & 1;
    const int sb = qh + 7 - jt;  // local seg index of this wave's window base

    // arrival barrier: prefetched data landed; prev jt's D2p/VT reads + PV done
    asm volatile("s_waitcnt vmcnt(0)" ::: "memory");
    __builtin_amdgcn_s_barrier();
    __builtin_amdgcn_sched_barrier(0);

    // prefetch jt+1 (in flight across the mid barrier)
    if (jt < 7) {
      STG(kbase + (size_t)(jt + 1) * 65536, Ks[cur ^ 1]);
      const int sg = 6 - jt;
      STG(pkw + (size_t)sg * 65536, PKs[sg & 3]);
      STG(pqw + (size_t)sg * 65536, PQs[sg & 3]);
      vreg[cur ^ 1] = *reinterpret_cast<const bf16x8*>(
          vbase + (size_t)((jt + 1) * 64 + (tid >> 3)) * 1024 + (tid & 7) * 8);
    }

    // VT build from V regs
    {
      const int j = tid >> 3, w0 = (tid & 7) * 8;
      bf16x8 vv = vreg[cur];
#pragma unroll
      for (int e = 0; e < 8; ++e) {
        int ch = (j >> 3) * 64 + w0 + e;
        ch ^= ((ch >> 3) & 7);
        VT[ch * 8 + (j & 7)] = vv[e];
      }
    }

    __builtin_amdgcn_s_setprio(1);
    // QK^T
    f32x4 sfr[4];
#pragma unroll
    for (int n = 0; n < 4; ++n) {
      const int j_ = n * 16 + li;
      bf16x8 b0 = *reinterpret_cast<const bf16x8*>(Ks[cur] + kchunk(j_, gr) * 8);
      bf16x8 b1 = *reinterpret_cast<const bf16x8*>(Ks[cur] + kchunk(j_, 4 + gr) * 8);
      f32x4 t = {};
      t = MFMA16(aq0, b0, t);
      t = MFMA16(aq1, b1, t);
      sfr[n] = t;
    }

    // c2p strip (wave-private, TRANSPOSED): DcpT[w][u=cg*16+li][ip base gr*4], b64 stores
#pragma unroll
    for (int cg = 0; cg < 5; ++cg) {
      const int b16 = wv + cg;
      const int slot = (sb + (b16 >> 2)) & 3;
      const int r64 = (b16 & 3) * 16 + li;
      bf16x8 p0 = *reinterpret_cast<const bf16x8*>(PKs[slot] + kchunk(r64, gr) * 8);
      bf16x8 p1 = *reinterpret_cast<const bf16x8*>(PKs[slot] + kchunk(r64, 4 + gr) * 8);
      f32x4 d = {};
      d = MFMA16(aq0, p0, d);
      d = MFMA16(aq1, p1, d);
      bf16x4 dv;
#pragma unroll
      for (int r = 0; r < 4; ++r) dv[r] = (bf16_t)d[r];
      *reinterpret_cast<bf16x4*>(&DcpT[w][cg * 16 + li][gr * 4]) = dv;
    }

    // p2c strip: wave covers jj in [wv*16,+16); store D2p[jj][ii+16] UNGUARDED (padded)
    const bf16x8 ak0 = *reinterpret_cast<const bf16x8*>(Ks[cur] + kchunk(wv * 16 + li, gr) * 8);
    const bf16x8 ak1 = *reinterpret_cast<const bf16x8*>(Ks[cur] + kchunk(wv * 16 + li, 4 + gr) * 8);
#pragma unroll
    for (int cg = 0; cg < 5; ++cg) {
      const int b16 = 3 - wv + cg;
      const int slot = (sb + (b16 >> 2)) & 3;
      const int r64 = (b16 & 3) * 16 + li;
      bf16x8 p0 = *reinterpret_cast<const bf16x8*>(PQs[slot] + kchunk(r64, gr) * 8);
      bf16x8 p1 = *reinterpret_cast<const bf16x8*>(PQs[slot] + kchunk(r64, 4 + gr) * 8);
      f32x4 d = {};
      d = MFMA16(ak0, p0, d);
      d = MFMA16(ak1, p1, d);
#pragma unroll
      for (int r = 0; r < 4; ++r) {
        const int jp = gr * 4 + r;                      // jj within strip
        const int c16 = cg * 16 + li + jp + 1;          // (ii = cg*16+li+jp-15) + 16
        D2p[qh][wv * 16 + jp][c16] = (bf16_t)d[r];
      }
    }
    __builtin_amdgcn_s_setprio(0);

    // mid barrier: VT + D2p cross-wave visible (DcpT/Pl need no barrier: per-wave)
    asm volatile("s_waitcnt lgkmcnt(0)" ::: "memory");
    __builtin_amdgcn_s_barrier();
    __builtin_amdgcn_sched_barrier(0);

    // gather biases + softmax + Pl
#pragma unroll
    for (int n = 0; n < 4; ++n) {
      const bf16x4 pvv =
          *reinterpret_cast<const bf16x4*>(&D2p[qh][n * 16 + li][wv * 16 + gr * 4 + 16]);
#pragma unroll
      for (int r = 0; r < 4; ++r) {
        const int ip = gr * 4 + r;
        const float c2 = (float)DcpT[w][ip + 63 - n * 16 - li][ip];
        const float s = sfr[n][r] + c2 + (float)pvv[r] - MCONST;
        const float pe = __builtin_amdgcn_exp2f(s);
        lsum[r] += pe;
        int ch = (n * 2 + (li >> 3)) * 16 + gr * 4 + r;
        ch ^= ((ch >> 3) & 7);
        Pl[w][ch * 8 + (li & 7)] = (bf16_t)pe;
      }
    }

    // Pl is per-wave: only drain LDS, no barrier before PV
    asm volatile("s_waitcnt lgkmcnt(0)" ::: "memory");
    __builtin_amdgcn_sched_barrier(0);

    // PV
    __builtin_amdgcn_s_setprio(1);
#pragma unroll
    for (int ks = 0; ks < 2; ++ks) {
      int chA = (ks * 4 + gr) * 16 + li;
      chA ^= ((chA >> 3) & 7);
      bf16x8 ap = *reinterpret_cast<const bf16x8*>(Pl[w] + chA * 8);
#pragma unroll
      for (int n2 = 0; n2 < 4; ++n2) {
        int chB = (ks * 4 + gr) * 64 + n2 * 16 + li;
        chB ^= ((chB >> 3) & 7);
        bf16x8 bvf = *reinterpret_cast<const bf16x8*>(VT + chB * 8);
        acc[n2] = MFMA16(ap, bvf, acc[n2]);
      }
    }
    __builtin_amdgcn_s_setprio(0);
  }
#undef STG

  // reduce lsum across the 16 li lanes, normalize, store
#pragma unroll
  for (int mm = 1; mm < 16; mm <<= 1)
#pragma unroll
    for (int r = 0; r < 4; ++r)
      lsum[r] += __shfl_xor(lsum[r], mm, 64);
  float invl[4];
#pragma unroll
  for (int r = 0; r < 4; ++r) invl[r] = 1.0f / lsum[r];

#pragma unroll
  for (int n2 = 0; n2 < 4; ++n2)
#pragma unroll
    for (int r = 0; r < 4; ++r) {
      const int i = i0 + wv * 16 + gr * 4 + r;
      const int wcol = n2 * 16 + li;
      out[(size_t)(b * 512 + i) * 1024 + h * 64 + wcol] = acc[n2][r] * invl[r];
    }
}

// ---------------------------------------------------------------- launch
extern "C" void kernel_launch(void* const* d_in, const int* in_sizes, int n_in,
                              void* d_out, int out_size, void* d_ws, size_t ws_size,
                              hipStream_t stream) {
  (void)in_sizes; (void)n_in; (void)out_size; (void)ws_size;
  const float* x   = (const float*)d_in[0];
  const float* rel = (const float*)d_in[1];
  const float* Wq  = (const float*)d_in[2];
  const float* bq  = (const float*)d_in[3];
  const float* Wk  = (const float*)d_in[4];
  const float* bk  = (const float*)d_in[5];
  const float* Wv  = (const float*)d_in[6];
  const float* bv  = (const float*)d_in[7];
  float* out = (float*)d_out;

  bf16_t* ws  = (bf16_t*)d_ws;
  bf16_t* xb  = ws;                 // 4 M elems
  bf16_t* wqb = xb + 4194304;       // 1 M each
  bf16_t* wkb = wqb + 1048576;
  bf16_t* wvb = wkb + 1048576;
  bf16_t* reb = wvb + 1048576;
  bf16_t* qbuf = reb + 1048576;     // 4 M each
  bf16_t* kbuf = qbuf + 4194304;
  bf16_t* vbuf = kbuf + 4194304;
  bf16_t* pkb = vbuf + 4194304;     // 1 M each
  bf16_t* pqb = pkb + 1048576;      // total ws ~44 MB

  cvt_all<<<4096, 256, 0, stream>>>(x, rel, Wq, Wk, Wv, ws);
  gemm_qkv<<<224, 512, 0, stream>>>(xb, reb, wqb, wkb, wvb,
                                    bq, bk, bv, qbuf, kbuf, vbuf, pkb, pqb);
  attn_mega<<<512, 512, 0, stream>>>(qbuf, kbuf, vbuf, pkb, pqb, out);
}